// Round 12
// baseline (53.110 us; speedup 1.0000x reference)
//
#include <hip/hip_runtime.h>

typedef _Float16 f16x8 __attribute__((ext_vector_type(8)));
typedef float f32x4 __attribute__((ext_vector_type(4)));

__device__ __forceinline__ f16x8 splat8(float v) {
  _Float16 h = (_Float16)v;
  return f16x8{h, h, h, h, h, h, h, h};
}

// XOR swizzle on f16-index for row-stride-64 tiles (16B-chunk granular):
// spreads 16-consecutive-row column reads across 8 bank groups.
__device__ __forceinline__ int swzh(int i) { return i ^ (((i >> 6) & 7) << 3); }

// ------- Kernel 1: x NCHW f32 -> xt NHWC f16 (1024 blks) + weight prep (216 blks) -------
__global__ __launch_bounds__(256) void k_xtprep(const float* __restrict__ x,
                                                const float* __restrict__ wt,
                                                const float* __restrict__ ow,
                                                _Float16* __restrict__ xt,
                                                _Float16* __restrict__ wb,
                                                _Float16* __restrict__ owb) {
  __shared__ float tile[64 * 65];
  int blk = blockIdx.x;
  int t = threadIdx.x;
  if (blk < 1024) {
    int b = blk >> 8;
    int y = (blk >> 1) & 127;
    int w0 = (blk & 1) * 64;
    const float* xp = x + ((size_t)(b * 64) * 128 + y) * 128 + w0;
#pragma unroll
    for (int it = 0; it < 4; ++it) {
      int idx = it * 256 + t;
      int c = idx >> 4, q = idx & 15;
      float4 v = *(const float4*)(xp + (size_t)c * 16384 + q * 4);
      float* tp = &tile[c * 65 + q * 4];
      tp[0] = v.x; tp[1] = v.y; tp[2] = v.z; tp[3] = v.w;
    }
    __syncthreads();
#pragma unroll
    for (int it = 0; it < 2; ++it) {
      int idx = it * 256 + t;
      int w = idx >> 3, c8 = idx & 7;
      f16x8 o;
#pragma unroll
      for (int j = 0; j < 8; ++j) o[j] = (_Float16)tile[(c8 * 8 + j) * 65 + w];
      *(f16x8*)&xt[(((size_t)b * 128 + y) * 128 + w0 + w) * 64 + c8 * 8] = o;
    }
  } else {
    int i = (blk - 1024) * 256 + t;
    if (i < 36864) {
      int k = i >> 12, rem = i & 4095, o = rem >> 6, c = rem & 63;
      wb[i] = (_Float16)wt[(o * 64 + c) * 9 + k];
    } else if (i < 36864 + 18432) {
      int j = i - 36864;
      int k = j >> 11, rem = j & 2047, o = rem >> 6, c = rem & 63;
      float v = (o < 18) ? ow[(o * 64 + c) * 9 + k] : 0.0f;
      owb[j] = (_Float16)v;
    }
  }
}

// ---------------- Kernel 2: fused deformable conv ----------------
// grid 1024 = (2 wtiles of 64px) x (128 h) x (4 b), XCD-chunk swizzled; 256 thr.
// Stage0: Xs[3][66][64] swizzled (zero-padded). 1 bar.
// Phase A: BARRIER-FREE offset conv: A-frags per-lane from owb (compiler-
//   pipelined, fully unrolled), B-frags from swizzled Xs. -> offL. 1 bar.
// Phase B: per tap {prefetch A-frags (regs) + gathers; sched_barrier;
//   MFMA tap k (A=regs, B=S-LDS); interp+write S[(k+1)&1]; bar}. No W-LDS.
__global__ __launch_bounds__(256, 4) void k_fused(
    const _Float16* __restrict__ xt, const _Float16* __restrict__ wb,
    const _Float16* __restrict__ owb, const float* __restrict__ ob,
    const float* __restrict__ bias, float* __restrict__ out) {
  // LDS (30464 B -> LDS allows 5, VGPR cap gives 4 blocks/CU):
  //  [0..25344)   Xs: [198][64] f16 swizzled  (Phase A; aliased by Sb)
  //  [0..16384)   Sb: 2 x [64][64] f16 swizzled (Phase B)
  //  [25344..30464) offL: [64][20] f32
  __shared__ char lds[30464];
  _Float16* Xs = (_Float16*)lds;
  _Float16* Sb = (_Float16*)lds;
  float* offL = (float*)(lds + 25344);

  int t = threadIdx.x;
  int lb = (blockIdx.x & 7) * 128 + (blockIdx.x >> 3);  // 1024 = 8 XCDs x 128
  int w0 = (lb & 1) * 64;
  int h = (lb >> 1) & 127;
  int b = lb >> 8;

  int lane = t & 63, wid = t >> 6;
  int row = lane & 15, quad = lane >> 4;
  const _Float16* xb = xt + (size_t)b * 128 * 128 * 64;

  // ======= Stage0: Xs rows h-1..h+1, px w0-1..w0+64 (66), 64c, swizzled =======
#pragma unroll
  for (int it = 0; it < 7; ++it) {
    int idx8 = it * 256 + t;  // 1584 chunks of f16x8
    if (idx8 < 1584) {
      int c8 = idx8 & 7;
      int jr = idx8 >> 3;  // 0..197
      int jj = jr % 66;
      int ki = jr / 66;
      int gy = h - 1 + ki;
      int gx = w0 - 1 + jj;
      f16x8 v = {};
      if (((unsigned)gy < 128u) & ((unsigned)gx < 128u))
        v = *(const f16x8*)(xb + ((size_t)gy * 128 + gx) * 64 + c8 * 8);
      *(f16x8*)&Xs[swzh(jr * 64 + c8 * 8)] = v;
    }
  }
  __syncthreads();

  // ======= Phase A: barrier-free offset conv (M=18pad32, N=64, K=576) =======
  {
    int woA = (wid >> 1) * 16;
    int wpA = (wid & 1) * 32;
    f32x4 accA[2];
    accA[0] = f32x4{0.f, 0.f, 0.f, 0.f};
    accA[1] = f32x4{0.f, 0.f, 0.f, 0.f};
#pragma unroll
    for (int k = 0; k < 9; ++k) {
      int ki = k / 3, kj = k % 3;
      const _Float16* ap = owb + k * 2048 + (woA + row) * 64 + quad * 8;
      f16x8 afr0 = *(const f16x8*)(ap);
      f16x8 afr1 = *(const f16x8*)(ap + 32);
#pragma unroll
      for (int n = 0; n < 2; ++n) {
        int j = wpA + n * 16 + row + kj;  // 0..65
        int bi = (ki * 66 + j) * 64 + quad * 8;
        f16x8 b0 = *(const f16x8*)&Xs[swzh(bi)];
        f16x8 b1 = *(const f16x8*)&Xs[swzh(bi + 32)];
        accA[n] = __builtin_amdgcn_mfma_f32_16x16x32_f16(afr0, b0, accA[n], 0, 0, 0);
        accA[n] = __builtin_amdgcn_mfma_f32_16x16x32_f16(afr1, b1, accA[n], 0, 0, 0);
      }
    }
    int qr = quad * 4;
#pragma unroll
    for (int n = 0; n < 2; ++n) {
#pragma unroll
      for (int r = 0; r < 4; ++r) {
        int co = woA + qr + r;
        if (co < 18)
          offL[(wpA + n * 16 + row) * 20 + co] = accA[n][r] + ob[co];
      }
    }
  }
  __syncthreads();  // offL visible; all Xs reads done -> Sb may be written

  // ======= Phase B =======
  int pix = t >> 2, cg = t & 3;
  int w = w0 + pix;
  int woB = (wid >> 1) * 32, wpB = (wid & 1) * 32;

  f16x8 wkA[4], wkB[4];  // A-frags [mi*2+ks], double-buffered in regs
  f16x8 ga0, ga1, gb0, gb1, gc0, gc1, gd0, gd1;
  float w00, w01, w10, w11;

  // per-lane A-frag source offset within a tap slice
  int wfo = row * 64 + quad * 8;

#define LOAD_WFRAG(KK, DST)                                                  \
  {                                                                          \
    const _Float16* wp_ = wb + (KK) * 4096 + woB * 64 + wfo;                 \
    DST[0] = *(const f16x8*)(wp_);                                           \
    DST[1] = *(const f16x8*)(wp_ + 32);                                      \
    DST[2] = *(const f16x8*)(wp_ + 1024);                                    \
    DST[3] = *(const f16x8*)(wp_ + 1024 + 32);                               \
  }

#define SAMPLE_ISSUE(KK)                                                     \
  {                                                                          \
    float dy = offL[pix * 20 + 2 * (KK)];                                    \
    float dx = offL[pix * 20 + 2 * (KK) + 1];                                \
    float py = dy + (float)(h + (KK) / 3 - 1);                               \
    float pxf = dx + (float)(w + (KK) % 3 - 1);                              \
    float fy = floorf(py), fx = floorf(pxf);                                 \
    float ly = py - fy, lx = pxf - fx;                                       \
    int y0 = (int)fy, x0 = (int)fx;                                          \
    int y1 = y0 + 1, x1 = x0 + 1;                                            \
    bool vy0 = (unsigned)y0 < 128u, vy1 = (unsigned)y1 < 128u;               \
    bool vx0 = (unsigned)x0 < 128u, vx1 = (unsigned)x1 < 128u;               \
    w00 = (vy0 && vx0) ? (1.f - ly) * (1.f - lx) : 0.f;                      \
    w01 = (vy0 && vx1) ? (1.f - ly) * lx : 0.f;                              \
    w10 = (vy1 && vx0) ? ly * (1.f - lx) : 0.f;                              \
    w11 = (vy1 && vx1) ? ly * lx : 0.f;                                      \
    int yc0 = min(max(y0, 0), 127), yc1 = min(max(y1, 0), 127);              \
    int xc0 = min(max(x0, 0), 127), xc1 = min(max(x1, 0), 127);              \
    const _Float16* p00 = xb + (yc0 * 128 + xc0) * 64 + cg * 16;             \
    int dxo = (xc1 - xc0) * 64, dyo = (yc1 - yc0) * 8192;                    \
    ga0 = *(const f16x8*)(p00);                                              \
    ga1 = *(const f16x8*)(p00 + 8);                                          \
    gb0 = *(const f16x8*)(p00 + dxo);                                        \
    gb1 = *(const f16x8*)(p00 + dxo + 8);                                    \
    gc0 = *(const f16x8*)(p00 + dyo);                                        \
    gc1 = *(const f16x8*)(p00 + dyo + 8);                                    \
    gd0 = *(const f16x8*)(p00 + dyo + dxo);                                  \
    gd1 = *(const f16x8*)(p00 + dyo + dxo + 8);                              \
  }

#define SAMPLE_FINISH(DSTBUF)                                                \
  {                                                                          \
    f16x8 W00 = splat8(w00), W01 = splat8(w01);                              \
    f16x8 W10 = splat8(w10), W11 = splat8(w11);                              \
    f16x8 s0 = W00 * ga0 + W01 * gb0 + W10 * gc0 + W11 * gd0;                \
    f16x8 s1 = W00 * ga1 + W01 * gb1 + W10 * gc1 + W11 * gd1;                \
    int si = (DSTBUF) * 4096 + pix * 64 + cg * 16;                           \
    *(f16x8*)&Sb[swzh(si)] = s0;                                             \
    *(f16x8*)&Sb[swzh(si + 8)] = s1;                                         \
  }

#define MFMA_TAP(BUF, WREG)                                                  \
  {                                                                          \
    int bufo = (BUF) * 4096;                                                 \
    _Pragma("unroll") for (int ks = 0; ks < 2; ++ks) {                       \
      int c0 = ks * 32 + quad * 8;                                           \
      f16x8 bfr[2];                                                          \
      _Pragma("unroll") for (int ni = 0; ni < 2; ++ni)                       \
          bfr[ni] =                                                          \
          *(const f16x8*)&Sb[swzh(bufo + (wpB + ni * 16 + row) * 64 + c0)];  \
      _Pragma("unroll") for (int mi = 0; mi < 2; ++mi)                       \
          _Pragma("unroll") for (int ni = 0; ni < 2; ++ni) acc[mi][ni] =     \
          __builtin_amdgcn_mfma_f32_16x16x32_f16(WREG[mi * 2 + ks], bfr[ni], \
                                                 acc[mi][ni], 0, 0, 0);      \
  }                                                                          \
  }

  f32x4 acc[2][2];
#pragma unroll
  for (int i = 0; i < 2; ++i)
#pragma unroll
    for (int j = 0; j < 2; ++j) acc[i][j] = f32x4{0.f, 0.f, 0.f, 0.f};

  // prologue: tap 0 -> S buf0 + wkA
  LOAD_WFRAG(0, wkA)
  SAMPLE_ISSUE(0)
  SAMPLE_FINISH(0)
  __syncthreads();

#define PHASEB_ITER(K, WCUR, WNXT)                                           \
  {                                                                          \
    LOAD_WFRAG((K) + 1, WNXT)                                                \
    SAMPLE_ISSUE((K) + 1)                                                    \
    __builtin_amdgcn_sched_barrier(0);                                       \
    MFMA_TAP((K) & 1, WCUR)                                                  \
    SAMPLE_FINISH(((K) + 1) & 1)                                             \
    __syncthreads();                                                         \
  }

  PHASEB_ITER(0, wkA, wkB)
  PHASEB_ITER(1, wkB, wkA)
  PHASEB_ITER(2, wkA, wkB)
  PHASEB_ITER(3, wkB, wkA)
  PHASEB_ITER(4, wkA, wkB)
  PHASEB_ITER(5, wkB, wkA)
  PHASEB_ITER(6, wkA, wkB)
  PHASEB_ITER(7, wkB, wkA)
  // tap 8: no prefetch, no finish
  MFMA_TAP(0, wkA)

#undef PHASEB_ITER
#undef MFMA_TAP
#undef SAMPLE_FINISH
#undef SAMPLE_ISSUE
#undef LOAD_WFRAG

  // ---- epilogue: col=lane&15 (pix), row=quad*4+r (o) ----
  {
    int col = lane & 15;
    int qr = quad * 4;
#pragma unroll
    for (int mi = 0; mi < 2; ++mi) {
#pragma unroll
      for (int ni = 0; ni < 2; ++ni) {
#pragma unroll
        for (int r = 0; r < 4; ++r) {
          int o = woB + mi * 16 + qr + r;
          int pw = w0 + wpB + ni * 16 + col;
          out[(((size_t)b * 64 + o) * 128 + h) * 128 + pw] = acc[mi][ni][r] + bias[o];
        }
      }
    }
  }
}

extern "C" void kernel_launch(void* const* d_in, const int* in_sizes, int n_in,
                              void* d_out, int out_size, void* d_ws,
                              size_t ws_size, hipStream_t stream) {
  const float* x = (const float*)d_in[0];       // (4,64,128,128)
  const float* ow = (const float*)d_in[1];      // (18,64,3,3)
  const float* ob = (const float*)d_in[2];      // (18,)
  const float* wt = (const float*)d_in[3];      // (64,64,3,3)
  const float* bias = (const float*)d_in[4];    // (64,)
  float* out = (float*)d_out;                   // (4,64,128,128)

  char* ws = (char*)d_ws;
  _Float16* xt = (_Float16*)ws;                      // 8,388,608 B
  _Float16* wb = (_Float16*)(ws + 8388608);          // 73,728 B
  _Float16* owb = (_Float16*)(ws + 8388608 + 73728); // 36,864 B

  k_xtprep<<<1240, 256, 0, stream>>>(x, wt, ow, xt, wb, owb);
  k_fused<<<1024, 256, 0, stream>>>(xt, wb, owb, ob, bias, out);
}

// Round 13
// 42.635 us; speedup vs baseline: 1.2457x; 1.2457x over previous
//
#include <hip/hip_runtime.h>

typedef _Float16 f16x8 __attribute__((ext_vector_type(8)));
typedef float f32x4 __attribute__((ext_vector_type(4)));

__device__ __forceinline__ f16x8 splat8(float v) {
  _Float16 h = (_Float16)v;
  return f16x8{h, h, h, h, h, h, h, h};
}

// XOR swizzle on f16-index for row-stride-64 tiles (16B-chunk granular)
__device__ __forceinline__ int swzh(int i) { return i ^ (((i >> 6) & 7) << 3); }

// ------- Kernel 1: x NCHW f32 -> xt NHWC f16 (1024 blks) + weight prep (216 blks) -------
__global__ __launch_bounds__(256) void k_xtprep(const float* __restrict__ x,
                                                const float* __restrict__ wt,
                                                const float* __restrict__ ow,
                                                _Float16* __restrict__ xt,
                                                _Float16* __restrict__ wb,
                                                _Float16* __restrict__ owb) {
  __shared__ float tile[64 * 65];
  int blk = blockIdx.x;
  int t = threadIdx.x;
  if (blk < 1024) {
    int b = blk >> 8;
    int y = (blk >> 1) & 127;
    int w0 = (blk & 1) * 64;
    const float* xp = x + ((size_t)(b * 64) * 128 + y) * 128 + w0;
#pragma unroll
    for (int it = 0; it < 4; ++it) {
      int idx = it * 256 + t;
      int c = idx >> 4, q = idx & 15;
      float4 v = *(const float4*)(xp + (size_t)c * 16384 + q * 4);
      float* tp = &tile[c * 65 + q * 4];
      tp[0] = v.x; tp[1] = v.y; tp[2] = v.z; tp[3] = v.w;
    }
    __syncthreads();
#pragma unroll
    for (int it = 0; it < 2; ++it) {
      int idx = it * 256 + t;
      int w = idx >> 3, c8 = idx & 7;
      f16x8 o;
#pragma unroll
      for (int j = 0; j < 8; ++j) o[j] = (_Float16)tile[(c8 * 8 + j) * 65 + w];
      *(f16x8*)&xt[(((size_t)b * 128 + y) * 128 + w0 + w) * 64 + c8 * 8] = o;
    }
  } else {
    int i = (blk - 1024) * 256 + t;
    if (i < 36864) {
      int k = i >> 12, rem = i & 4095, o = rem >> 6, c = rem & 63;
      wb[i] = (_Float16)wt[(o * 64 + c) * 9 + k];
    } else if (i < 36864 + 18432) {
      int j = i - 36864;
      int k = j >> 11, rem = j & 2047, o = rem >> 6, c = rem & 63;
      float v = (o < 18) ? ow[(o * 64 + c) * 9 + k] : 0.0f;
      owb[j] = (_Float16)v;
    }
  }
}

// ---------------- Kernel 2: fused deformable conv, 32px tiles ----------------
// grid 2048 = (4 wtiles of 32px) x (128 h) x (4 b), XCD-chunk swizzled; 256 thr.
// Proven R10 skeleton (all MFMA operands from LDS, cooperative staging),
// resized 64px -> 32px: LDS 21.2 KB -> 7 blocks/CU (vs 4), 87% occ ceiling.
__global__ __launch_bounds__(256, 4) void k_fused(
    const _Float16* __restrict__ xt, const _Float16* __restrict__ wb,
    const _Float16* __restrict__ owb, const float* __restrict__ ob,
    const float* __restrict__ bias, float* __restrict__ out) {
  // LDS (21248 B -> 7 blocks/CU):
  //  region0 [0..13056): Xs [102][64] f16 swz (Phase A)
  //                      aliased in Phase B by Sb [32][64] @0 (4096 B)
  //                      and Wp [64][64] @4096 (8192 B)
  //  region1 [13056..21248): owbp 2x[32][64] f16 swz (Phase A)
  //                          aliased by offL [32][20] f32 (2560 B)
  __shared__ char lds[21248];
  _Float16* Xs = (_Float16*)lds;
  _Float16* Sb = (_Float16*)lds;
  _Float16* Wp = (_Float16*)(lds + 4096);
  _Float16* owbp = (_Float16*)(lds + 13056);
  float* offL = (float*)(lds + 13056);

  int t = threadIdx.x;
  int lb = (blockIdx.x & 7) * 256 + (blockIdx.x >> 3);  // 2048 = 8 XCDs x 256
  int w0 = (lb & 3) * 32;
  int h = (lb >> 2) & 127;
  int b = lb >> 9;

  int lane = t & 63, wid = t >> 6;
  int row = lane & 15, quad = lane >> 4;
  const _Float16* xb = xt + (size_t)b * 128 * 128 * 64;

  // ======= Stage0: Xs rows h-1..h+1, px w0-1..w0+32 (34), 64c, swizzled =======
#pragma unroll
  for (int it = 0; it < 4; ++it) {
    int idx8 = it * 256 + t;  // 816 chunks of f16x8
    if (idx8 < 816) {
      int c8 = idx8 & 7;
      int jr = idx8 >> 3;  // 0..101
      int jj = jr % 34;
      int ki = jr / 34;
      int gy = h - 1 + ki;
      int gx = w0 - 1 + jj;
      f16x8 v = {};
      if (((unsigned)gy < 128u) & ((unsigned)gx < 128u))
        v = *(const f16x8*)(xb + ((size_t)gy * 128 + gx) * 64 + c8 * 8);
      *(f16x8*)&Xs[swzh(jr * 64 + c8 * 8)] = v;
    }
  }
  // stage owb tap 0 -> owbp buf0 (256 chunks, 1/thread)
  {
    int o = t >> 3, c8 = t & 7;
    *(f16x8*)&owbp[swzh(o * 64 + c8 * 8)] = ((const f16x8*)owb)[t];
  }
  __syncthreads();

  // ======= Phase A: offset conv (M=18pad32, N=32px, K=576), owb dbuf =======
  {
    int woA = (wid >> 1) * 16;  // o half
    int wpA = (wid & 1) * 16;   // px half
    f32x4 accA = f32x4{0.f, 0.f, 0.f, 0.f};
#pragma unroll
    for (int k = 0; k < 9; ++k) {
      if (k < 8) {  // stage owb tap k+1 -> other buffer
        int o = t >> 3, c8 = t & 7;
        f16x8 v = ((const f16x8*)(owb + (k + 1) * 2048))[t];
        *(f16x8*)&owbp[swzh(((k + 1) & 1) * 2048 + o * 64 + c8 * 8)] = v;
      }
      int ki = k / 3, kj = k % 3;
      int ai = (k & 1) * 2048 + (woA + row) * 64 + quad * 8;
      f16x8 afr0 = *(const f16x8*)&owbp[swzh(ai)];
      f16x8 afr1 = *(const f16x8*)&owbp[swzh(ai + 32)];
      int j = wpA + row + kj;  // 0..33
      int bi = (ki * 34 + j) * 64 + quad * 8;
      f16x8 b0 = *(const f16x8*)&Xs[swzh(bi)];
      f16x8 b1 = *(const f16x8*)&Xs[swzh(bi + 32)];
      accA = __builtin_amdgcn_mfma_f32_16x16x32_f16(afr0, b0, accA, 0, 0, 0);
      accA = __builtin_amdgcn_mfma_f32_16x16x32_f16(afr1, b1, accA, 0, 0, 0);
      __syncthreads();
    }
    // offL aliases owbp; all owbp reads are behind tap-8's barrier.
    int qr = quad * 4;
#pragma unroll
    for (int r = 0; r < 4; ++r) {
      int co = woA + qr + r;
      if (co < 18) offL[(wpA + row) * 20 + co] = accA[r] + ob[co];
    }
  }
  __syncthreads();  // offL visible; Xs dead -> Sb/Wp writable

  // ======= Phase B: per tap {stage Wk + sample S; bar; MFMA; bar} =======
  int pix = t >> 3, cg = t & 7;  // 32 px x 8 ch-groups
  int w = w0 + pix;
  int woB = (wid >> 1) * 32, wpB = (wid & 1) * 16;

  f32x4 acc[2];
  acc[0] = f32x4{0.f, 0.f, 0.f, 0.f};
  acc[1] = f32x4{0.f, 0.f, 0.f, 0.f};

  for (int k = 0; k < 9; ++k) {
    // ---- stage Wk: wb[k][64][64] -> Wp (swz), 2 chunks/thread ----
    {
      const f16x8* wsrc = (const f16x8*)(wb + k * 4096);
#pragma unroll
      for (int r = 0; r < 2; ++r) {
        int idx8 = r * 256 + t;
        int o = idx8 >> 3, c8 = idx8 & 7;
        *(f16x8*)&Wp[swzh(o * 64 + c8 * 8)] = wsrc[idx8];
      }
    }
    // ---- sample S[pix][cg*8..+8] for this tap (4 gathers + f16 interp) ----
    {
      int ki = k / 3, kj = k % 3;
      float dy = offL[pix * 20 + 2 * k];
      float dx = offL[pix * 20 + 2 * k + 1];
      float py = dy + (float)(h + ki - 1);
      float pxf = dx + (float)(w + kj - 1);
      float fy = floorf(py), fx = floorf(pxf);
      float ly = py - fy, lx = pxf - fx;
      int y0 = (int)fy, x0 = (int)fx;
      int y1 = y0 + 1, x1 = x0 + 1;
      bool vy0 = (unsigned)y0 < 128u, vy1 = (unsigned)y1 < 128u;
      bool vx0 = (unsigned)x0 < 128u, vx1 = (unsigned)x1 < 128u;
      float w00 = (vy0 && vx0) ? (1.f - ly) * (1.f - lx) : 0.f;
      float w01 = (vy0 && vx1) ? (1.f - ly) * lx : 0.f;
      float w10 = (vy1 && vx0) ? ly * (1.f - lx) : 0.f;
      float w11 = (vy1 && vx1) ? ly * lx : 0.f;
      int yc0 = min(max(y0, 0), 127), yc1 = min(max(y1, 0), 127);
      int xc0 = min(max(x0, 0), 127), xc1 = min(max(x1, 0), 127);
      const _Float16* p00 = xb + (yc0 * 128 + xc0) * 64 + cg * 8;
      int dxo = (xc1 - xc0) * 64, dyo = (yc1 - yc0) * 8192;
      f16x8 ga = *(const f16x8*)(p00);
      f16x8 gb = *(const f16x8*)(p00 + dxo);
      f16x8 gc = *(const f16x8*)(p00 + dyo);
      f16x8 gd = *(const f16x8*)(p00 + dyo + dxo);
      f16x8 s = splat8(w00) * ga + splat8(w01) * gb + splat8(w10) * gc +
                splat8(w11) * gd;
      *(f16x8*)&Sb[swzh(pix * 64 + cg * 8)] = s;
    }
    __syncthreads();
    // ---- MFMA: all operands from LDS ----
    {
#pragma unroll
      for (int ks = 0; ks < 2; ++ks) {
        int c0 = ks * 32 + quad * 8;
        f16x8 bfr = *(const f16x8*)&Sb[swzh((wpB + row) * 64 + c0)];
#pragma unroll
        for (int mi = 0; mi < 2; ++mi) {
          f16x8 afr = *(const f16x8*)&Wp[swzh((woB + mi * 16 + row) * 64 + c0)];
          acc[mi] = __builtin_amdgcn_mfma_f32_16x16x32_f16(afr, bfr, acc[mi], 0, 0, 0);
        }
      }
    }
    __syncthreads();
  }
  // ---- epilogue: col=lane&15 (px), row=quad*4+r (o) ----
  {
    int col = lane & 15;
    int qr = quad * 4;
#pragma unroll
    for (int mi = 0; mi < 2; ++mi) {
#pragma unroll
      for (int r = 0; r < 4; ++r) {
        int o = woB + mi * 16 + qr + r;
        out[(((size_t)b * 64 + o) * 128 + h) * 128 + w0 + wpB + col] =
            acc[mi][r] + bias[o];
      }
    }
  }
}

extern "C" void kernel_launch(void* const* d_in, const int* in_sizes, int n_in,
                              void* d_out, int out_size, void* d_ws,
                              size_t ws_size, hipStream_t stream) {
  const float* x = (const float*)d_in[0];       // (4,64,128,128)
  const float* ow = (const float*)d_in[1];      // (18,64,3,3)
  const float* ob = (const float*)d_in[2];      // (18,)
  const float* wt = (const float*)d_in[3];      // (64,64,3,3)
  const float* bias = (const float*)d_in[4];    // (64,)
  float* out = (float*)d_out;                   // (4,64,128,128)

  char* ws = (char*)d_ws;
  _Float16* xt = (_Float16*)ws;                      // 8,388,608 B
  _Float16* wb = (_Float16*)(ws + 8388608);          // 73,728 B
  _Float16* owb = (_Float16*)(ws + 8388608 + 73728); // 36,864 B

  k_xtprep<<<1240, 256, 0, stream>>>(x, wt, ow, xt, wb, owb);
  k_fused<<<2048, 256, 0, stream>>>(xt, wb, owb, ob, bias, out);
}

// Round 14
// 41.063 us; speedup vs baseline: 1.2934x; 1.0383x over previous
//
#include <hip/hip_runtime.h>

typedef _Float16 f16x8 __attribute__((ext_vector_type(8)));
typedef float f32x4 __attribute__((ext_vector_type(4)));

__device__ __forceinline__ f16x8 splat8(float v) {
  _Float16 h = (_Float16)v;
  return f16x8{h, h, h, h, h, h, h, h};
}

// XOR swizzle on f16-index for row-stride-64 tiles (16B-chunk granular)
__device__ __forceinline__ int swzh(int i) { return i ^ (((i >> 6) & 7) << 3); }

// ------- Kernel 1: x NCHW f32 -> xt NHWC f16 (1024 blks) + weight prep (216 blks) -------
__global__ __launch_bounds__(256) void k_xtprep(const float* __restrict__ x,
                                                const float* __restrict__ wt,
                                                const float* __restrict__ ow,
                                                _Float16* __restrict__ xt,
                                                _Float16* __restrict__ wb,
                                                _Float16* __restrict__ owb) {
  __shared__ float tile[64 * 65];
  int blk = blockIdx.x;
  int t = threadIdx.x;
  if (blk < 1024) {
    int b = blk >> 8;
    int y = (blk >> 1) & 127;
    int w0 = (blk & 1) * 64;
    const float* xp = x + ((size_t)(b * 64) * 128 + y) * 128 + w0;
#pragma unroll
    for (int it = 0; it < 4; ++it) {
      int idx = it * 256 + t;
      int c = idx >> 4, q = idx & 15;
      float4 v = *(const float4*)(xp + (size_t)c * 16384 + q * 4);
      float* tp = &tile[c * 65 + q * 4];
      tp[0] = v.x; tp[1] = v.y; tp[2] = v.z; tp[3] = v.w;
    }
    __syncthreads();
#pragma unroll
    for (int it = 0; it < 2; ++it) {
      int idx = it * 256 + t;
      int w = idx >> 3, c8 = idx & 7;
      f16x8 o;
#pragma unroll
      for (int j = 0; j < 8; ++j) o[j] = (_Float16)tile[(c8 * 8 + j) * 65 + w];
      *(f16x8*)&xt[(((size_t)b * 128 + y) * 128 + w0 + w) * 64 + c8 * 8] = o;
    }
  } else {
    int i = (blk - 1024) * 256 + t;
    if (i < 36864) {
      int k = i >> 12, rem = i & 4095, o = rem >> 6, c = rem & 63;
      wb[i] = (_Float16)wt[(o * 64 + c) * 9 + k];
    } else if (i < 36864 + 18432) {
      int j = i - 36864;
      int k = j >> 11, rem = j & 2047, o = rem >> 6, c = rem & 63;
      float v = (o < 18) ? ow[(o * 64 + c) * 9 + k] : 0.0f;
      owb[j] = (_Float16)v;
    }
  }
}

// ---------------- Kernel 2: fused deformable conv, 3-tap batches ----------------
// grid 2048 = (4 wtiles of 32px) x (128 h) x (4 b), XCD-chunk swizzled; 256 thr.
// All MFMA operands from LDS (proven R10). NEW: 3 taps per barrier phase:
// 12 independent gathers in flight per thread per exposure; exposures 9 -> 3.
__global__ __launch_bounds__(256, 4) void k_fused(
    const _Float16* __restrict__ xt, const _Float16* __restrict__ wb,
    const _Float16* __restrict__ owb, const float* __restrict__ ob,
    const float* __restrict__ bias, float* __restrict__ out) {
  // LDS 39,424 B -> 4 blocks/CU:
  //  Phase B: S3 [3][32][64] @0 (12,288) | Wp3 [3][64][64] @12,288 (24,576)
  //  Phase A: Xs [102][64] @0 (13,056)   | owbp3 [3][32][64] @13,056 (12,288)
  //  offL [32][20] f32 @36,864 (2,560) — disjoint always
  __shared__ char lds[39424];
  _Float16* S3 = (_Float16*)lds;
  _Float16* Wp3 = (_Float16*)(lds + 12288);
  _Float16* Xs = (_Float16*)lds;
  _Float16* owbp3 = (_Float16*)(lds + 13056);
  float* offL = (float*)(lds + 36864);

  int t = threadIdx.x;
  int lb = (blockIdx.x & 7) * 256 + (blockIdx.x >> 3);  // 2048 = 8 XCDs x 256
  int w0 = (lb & 3) * 32;
  int h = (lb >> 2) & 127;
  int b = lb >> 9;

  int lane = t & 63, wid = t >> 6;
  int row = lane & 15, quad = lane >> 4;
  const _Float16* xb = xt + (size_t)b * 128 * 128 * 64;

  // ======= Stage0: Xs rows h-1..h+1, px w0-1..w0+32 (34), 64c, swizzled =======
#pragma unroll
  for (int it = 0; it < 4; ++it) {
    int idx8 = it * 256 + t;  // 816 chunks of f16x8
    if (idx8 < 816) {
      int c8 = idx8 & 7;
      int jr = idx8 >> 3;  // 0..101
      int jj = jr % 34;
      int ki = jr / 34;
      int gy = h - 1 + ki;
      int gx = w0 - 1 + jj;
      f16x8 v = {};
      if (((unsigned)gy < 128u) & ((unsigned)gx < 128u))
        v = *(const f16x8*)(xb + ((size_t)gy * 128 + gx) * 64 + c8 * 8);
      *(f16x8*)&Xs[swzh(jr * 64 + c8 * 8)] = v;
    }
  }
  __syncthreads();

  // ======= Phase A: offset conv (M=18pad32, N=32px, K=576), 3-tap batches =======
  {
    int woA = (wid >> 1) * 16;  // o half
    int wpA = (wid & 1) * 16;   // px half
    f32x4 accA = f32x4{0.f, 0.f, 0.f, 0.f};
#pragma unroll
    for (int bt = 0; bt < 3; ++bt) {
      // stage taps 3bt..3bt+2 (3 chunks/thread, 12 loads in flight block-wide)
      {
        int o = t >> 3, c8 = t & 7;
#pragma unroll
        for (int kb = 0; kb < 3; ++kb)
          *(f16x8*)&owbp3[swzh(kb * 2048 + o * 64 + c8 * 8)] =
              *(const f16x8*)(owb + (bt * 3 + kb) * 2048 + t * 8);
      }
      __syncthreads();
#pragma unroll
      for (int kb = 0; kb < 3; ++kb) {
        // k = bt*3+kb -> ki = bt, kj = kb
        int ai = kb * 2048 + (woA + row) * 64 + quad * 8;
        f16x8 afr0 = *(const f16x8*)&owbp3[swzh(ai)];
        f16x8 afr1 = *(const f16x8*)&owbp3[swzh(ai + 32)];
        int j = wpA + row + kb;  // 0..33
        int bi = (bt * 34 + j) * 64 + quad * 8;
        f16x8 b0 = *(const f16x8*)&Xs[swzh(bi)];
        f16x8 b1 = *(const f16x8*)&Xs[swzh(bi + 32)];
        accA = __builtin_amdgcn_mfma_f32_16x16x32_f16(afr0, b0, accA, 0, 0, 0);
        accA = __builtin_amdgcn_mfma_f32_16x16x32_f16(afr1, b1, accA, 0, 0, 0);
      }
      __syncthreads();
    }
    // all Phase-A LDS reads are behind the last barrier; offL is disjoint.
    int qr = quad * 4;
#pragma unroll
    for (int r = 0; r < 4; ++r) {
      int co = woA + qr + r;
      if (co < 18) offL[(wpA + row) * 20 + co] = accA[r] + ob[co];
    }
  }
  __syncthreads();  // offL visible; Xs/owbp3 dead -> S3/Wp3 writable

  // ======= Phase B: 3 batches of 3 taps {stage W3 + sample 3; bar; MFMA; bar} =======
  int pix = t >> 3, cg = t & 7;  // 32 px x 8 ch-groups
  int w = w0 + pix;
  int woB = (wid >> 1) * 32, wpB = (wid & 1) * 16;

  f32x4 acc[2];
  acc[0] = f32x4{0.f, 0.f, 0.f, 0.f};
  acc[1] = f32x4{0.f, 0.f, 0.f, 0.f};

#pragma unroll
  for (int bt = 0; bt < 3; ++bt) {
    // ---- stage W for 3 taps (6 chunks/thread) ----
    {
#pragma unroll
      for (int kb = 0; kb < 3; ++kb) {
        const f16x8* wsrc = (const f16x8*)(wb + (bt * 3 + kb) * 4096);
#pragma unroll
        for (int r = 0; r < 2; ++r) {
          int idx8 = r * 256 + t;
          int o = idx8 >> 3, c8 = idx8 & 7;
          *(f16x8*)&Wp3[swzh(kb * 4096 + o * 64 + c8 * 8)] = wsrc[idx8];
        }
      }
    }
    // ---- sample 3 taps: addresses+weights first, then 12 loads, then interp ----
    {
      float wt4[3][4];
      const _Float16* pb[3];
      int pdx[3], pdy[3];
#pragma unroll
      for (int kb = 0; kb < 3; ++kb) {
        // k = bt*3+kb -> ki = bt, kj = kb
        int k = bt * 3 + kb;
        float dy = offL[pix * 20 + 2 * k];
        float dx = offL[pix * 20 + 2 * k + 1];
        float py = dy + (float)(h + bt - 1);
        float pxf = dx + (float)(w + kb - 1);
        float fy = floorf(py), fx = floorf(pxf);
        float ly = py - fy, lx = pxf - fx;
        int y0 = (int)fy, x0 = (int)fx;
        int y1 = y0 + 1, x1 = x0 + 1;
        bool vy0 = (unsigned)y0 < 128u, vy1 = (unsigned)y1 < 128u;
        bool vx0 = (unsigned)x0 < 128u, vx1 = (unsigned)x1 < 128u;
        wt4[kb][0] = (vy0 && vx0) ? (1.f - ly) * (1.f - lx) : 0.f;
        wt4[kb][1] = (vy0 && vx1) ? (1.f - ly) * lx : 0.f;
        wt4[kb][2] = (vy1 && vx0) ? ly * (1.f - lx) : 0.f;
        wt4[kb][3] = (vy1 && vx1) ? ly * lx : 0.f;
        int yc0 = min(max(y0, 0), 127), yc1 = min(max(y1, 0), 127);
        int xc0 = min(max(x0, 0), 127), xc1 = min(max(x1, 0), 127);
        pb[kb] = xb + (yc0 * 128 + xc0) * 64 + cg * 8;
        pdx[kb] = (xc1 - xc0) * 64;
        pdy[kb] = (yc1 - yc0) * 8192;
      }
      f16x8 g[3][4];
#pragma unroll
      for (int kb = 0; kb < 3; ++kb) {
        g[kb][0] = *(const f16x8*)(pb[kb]);
        g[kb][1] = *(const f16x8*)(pb[kb] + pdx[kb]);
        g[kb][2] = *(const f16x8*)(pb[kb] + pdy[kb]);
        g[kb][3] = *(const f16x8*)(pb[kb] + pdy[kb] + pdx[kb]);
      }
#pragma unroll
      for (int kb = 0; kb < 3; ++kb) {
        f16x8 s = splat8(wt4[kb][0]) * g[kb][0] + splat8(wt4[kb][1]) * g[kb][1] +
                  splat8(wt4[kb][2]) * g[kb][2] + splat8(wt4[kb][3]) * g[kb][3];
        *(f16x8*)&S3[swzh(kb * 2048 + pix * 64 + cg * 8)] = s;
      }
    }
    __syncthreads();
    // ---- MFMA: 3 taps x {2 ks x 2 mi}, all operands from LDS ----
    {
#pragma unroll
      for (int kb = 0; kb < 3; ++kb) {
#pragma unroll
        for (int ks = 0; ks < 2; ++ks) {
          int c0 = ks * 32 + quad * 8;
          f16x8 bfr = *(const f16x8*)&S3[swzh(kb * 2048 + (wpB + row) * 64 + c0)];
#pragma unroll
          for (int mi = 0; mi < 2; ++mi) {
            f16x8 afr =
                *(const f16x8*)&Wp3[swzh(kb * 4096 + (woB + mi * 16 + row) * 64 + c0)];
            acc[mi] = __builtin_amdgcn_mfma_f32_16x16x32_f16(afr, bfr, acc[mi], 0, 0, 0);
          }
        }
      }
    }
    __syncthreads();
  }
  // ---- epilogue: col=lane&15 (px), row=quad*4+r (o) ----
  {
    int col = lane & 15;
    int qr = quad * 4;
#pragma unroll
    for (int mi = 0; mi < 2; ++mi) {
#pragma unroll
      for (int r = 0; r < 4; ++r) {
        int o = woB + mi * 16 + qr + r;
        out[(((size_t)b * 64 + o) * 128 + h) * 128 + w0 + wpB + col] =
            acc[mi][r] + bias[o];
      }
    }
  }
}

extern "C" void kernel_launch(void* const* d_in, const int* in_sizes, int n_in,
                              void* d_out, int out_size, void* d_ws,
                              size_t ws_size, hipStream_t stream) {
  const float* x = (const float*)d_in[0];       // (4,64,128,128)
  const float* ow = (const float*)d_in[1];      // (18,64,3,3)
  const float* ob = (const float*)d_in[2];      // (18,)
  const float* wt = (const float*)d_in[3];      // (64,64,3,3)
  const float* bias = (const float*)d_in[4];    // (64,)
  float* out = (float*)d_out;                   // (4,64,128,128)

  char* ws = (char*)d_ws;
  _Float16* xt = (_Float16*)ws;                      // 8,388,608 B
  _Float16* wb = (_Float16*)(ws + 8388608);          // 73,728 B
  _Float16* owb = (_Float16*)(ws + 8388608 + 73728); // 36,864 B

  k_xtprep<<<1240, 256, 0, stream>>>(x, wt, ow, xt, wb, owb);
  k_fused<<<2048, 256, 0, stream>>>(xt, wb, owb, ob, bias, out);
}

// Round 16
// 35.824 us; speedup vs baseline: 1.4825x; 1.1462x over previous
//
#include <hip/hip_runtime.h>

typedef _Float16 f16x8 __attribute__((ext_vector_type(8)));
typedef float f32x4 __attribute__((ext_vector_type(4)));

__device__ __forceinline__ f16x8 splat8(float v) {
  _Float16 h = (_Float16)v;
  return f16x8{h, h, h, h, h, h, h, h};
}

// XOR swizzle on f16-index for row-stride-64 tiles (16B-chunk granular)
__device__ __forceinline__ int swzh(int i) { return i ^ (((i >> 6) & 7) << 3); }

// ------- Kernel 1: x NCHW f32 -> xt NHWC f16 (1024 blks) + weight prep (216 blks) -------
__global__ __launch_bounds__(256) void k_xtprep(const float* __restrict__ x,
                                                const float* __restrict__ wt,
                                                const float* __restrict__ ow,
                                                _Float16* __restrict__ xt,
                                                _Float16* __restrict__ wb,
                                                _Float16* __restrict__ owb) {
  __shared__ float tile[64 * 65];
  int blk = blockIdx.x;
  int t = threadIdx.x;
  if (blk < 1024) {
    int b = blk >> 8;
    int y = (blk >> 1) & 127;
    int w0 = (blk & 1) * 64;
    const float* xp = x + ((size_t)(b * 64) * 128 + y) * 128 + w0;
#pragma unroll
    for (int it = 0; it < 4; ++it) {
      int idx = it * 256 + t;
      int c = idx >> 4, q = idx & 15;
      float4 v = *(const float4*)(xp + (size_t)c * 16384 + q * 4);
      float* tp = &tile[c * 65 + q * 4];
      tp[0] = v.x; tp[1] = v.y; tp[2] = v.z; tp[3] = v.w;
    }
    __syncthreads();
#pragma unroll
    for (int it = 0; it < 2; ++it) {
      int idx = it * 256 + t;
      int w = idx >> 3, c8 = idx & 7;
      f16x8 o;
#pragma unroll
      for (int j = 0; j < 8; ++j) o[j] = (_Float16)tile[(c8 * 8 + j) * 65 + w];
      *(f16x8*)&xt[(((size_t)b * 128 + y) * 128 + w0 + w) * 64 + c8 * 8] = o;
    }
  } else {
    int i = (blk - 1024) * 256 + t;
    if (i < 36864) {
      int k = i >> 12, rem = i & 4095, o = rem >> 6, c = rem & 63;
      wb[i] = (_Float16)wt[(o * 64 + c) * 9 + k];
    } else if (i < 36864 + 18432) {
      int j = i - 36864;
      int k = j >> 11, rem = j & 2047, o = rem >> 6, c = rem & 63;
      float v = (o < 18) ? ow[(o * 64 + c) * 9 + k] : 0.0f;
      owb[j] = (_Float16)v;
    }
  }
}

// ---------------- Kernel 2: fused deformable conv, 4h x 32px tiles ----------------
// grid 512 = (4 wtiles) x (32 h-quads) x (4 b), XCD swizzled; 512 threads (8 waves).
// W traffic 147 MB -> 38 MB (blocks 2048 -> 512). Phase A: 4 barriers total.
// Phase B: W3 batches dbuf-staged one batch ahead; S single-buf 2-bar/tap (proven).
__global__ __launch_bounds__(512, 2) void k_fused(
    const _Float16* __restrict__ xt, const _Float16* __restrict__ wb,
    const _Float16* __restrict__ owb, const float* __restrict__ ob,
    const float* __restrict__ bias, float* __restrict__ out) {
  // LDS 75,776 B -> 2 blocks/CU:
  //  Phase B: Wp3 2x[3][64][64] @0 (49,152) | S [128][64] @49,152 (16,384)
  //  Phase A: Xs [204][64] @0 (26,112) | owbL 2x[3][32][64] @26,112 (24,576)
  //  offL [128][20] f32 @65,536 (10,240) — disjoint
  __shared__ char lds[75776];
  _Float16* Wp3 = (_Float16*)lds;
  _Float16* S = (_Float16*)(lds + 49152);
  _Float16* Xs = (_Float16*)lds;
  _Float16* owbL = (_Float16*)(lds + 26112);
  float* offL = (float*)(lds + 65536);

  int t = threadIdx.x;
  int lb = (blockIdx.x & 7) * 64 + (blockIdx.x >> 3);  // 512 = 8 XCDs x 64
  int w0 = (lb & 3) * 32;
  int h0 = ((lb >> 2) & 31) * 4;
  int b = lb >> 7;

  int lane = t & 63, wid = t >> 6;
  int lr = lane & 15, quad = lane >> 4;
  const _Float16* xb = xt + (size_t)b * 128 * 128 * 64;

  // ======= Stage0: Xs rows h0-1..h0+4 (6), px w0-1..w0+32 (34), 64c + owb batch0 =======
#pragma unroll
  for (int it = 0; it < 4; ++it) {
    int idx8 = it * 512 + t;  // 1632 chunks
    if (idx8 < 1632) {
      int c8 = idx8 & 7;
      int jr = idx8 >> 3;  // 0..203
      int col = jr % 34;
      int xr = jr / 34;
      int gy = h0 - 1 + xr;
      int gx = w0 - 1 + col;
      f16x8 v = {};
      if (((unsigned)gy < 128u) & ((unsigned)gx < 128u))
        v = *(const f16x8*)(xb + ((size_t)gy * 128 + gx) * 64 + c8 * 8);
      *(f16x8*)&Xs[swzh(jr * 64 + c8 * 8)] = v;
    }
  }
#pragma unroll
  for (int it = 0; it < 2; ++it) {  // owb taps 0..2 -> owbL buf0 (256 chunks/tap)
    int idx8 = it * 512 + t;
    if (idx8 < 768) {
      int kb = idx8 >> 8, rem = idx8 & 255;
      int o = rem >> 3, c8 = rem & 7;
      *(f16x8*)&owbL[swzh(kb * 2048 + o * 64 + c8 * 8)] =
          ((const f16x8*)(owb + kb * 2048))[rem];
    }
  }

  // ======= Phase A: offset conv (M=18pad32, N=128px, K=576), 4 barriers =======
  {
    int oh = (wid >> 2) * 16;  // o-half base
    int ar = wid & 3;          // output row 0..3
    f32x4 accA[2];
    accA[0] = f32x4{0.f, 0.f, 0.f, 0.f};
    accA[1] = f32x4{0.f, 0.f, 0.f, 0.f};
#pragma unroll
    for (int bt = 0; bt < 3; ++bt) {
      __syncthreads();  // staging of batch bt complete
#pragma unroll
      for (int kb = 0; kb < 3; ++kb) {
        int ai = (bt & 1) * 6144 + kb * 2048 + (oh + lr) * 64 + quad * 8;
        f16x8 afr0 = *(const f16x8*)&owbL[swzh(ai)];
        f16x8 afr1 = *(const f16x8*)&owbL[swzh(ai + 32)];
#pragma unroll
        for (int ni = 0; ni < 2; ++ni) {
          int j = ni * 16 + lr + kb;  // 0..33
          int bi = ((ar + bt) * 34 + j) * 64 + quad * 8;
          f16x8 b0 = *(const f16x8*)&Xs[swzh(bi)];
          f16x8 b1 = *(const f16x8*)&Xs[swzh(bi + 32)];
          accA[ni] = __builtin_amdgcn_mfma_f32_16x16x32_f16(afr0, b0, accA[ni], 0, 0, 0);
          accA[ni] = __builtin_amdgcn_mfma_f32_16x16x32_f16(afr1, b1, accA[ni], 0, 0, 0);
        }
      }
      if (bt < 2) {  // stage batch bt+1 -> other buffer (overlaps other waves' MFMA)
#pragma unroll
        for (int it = 0; it < 2; ++it) {
          int idx8 = it * 512 + t;
          if (idx8 < 768) {
            int kb = idx8 >> 8, rem = idx8 & 255;
            int o = rem >> 3, c8 = rem & 7;
            *(f16x8*)&owbL[swzh(((bt + 1) & 1) * 6144 + kb * 2048 + o * 64 + c8 * 8)] =
                ((const f16x8*)(owb + ((bt + 1) * 3 + kb) * 2048))[rem];
          }
        }
      }
    }
    // offL disjoint; write directly
    int qr = quad * 4;
#pragma unroll
    for (int ni = 0; ni < 2; ++ni) {
#pragma unroll
      for (int r = 0; r < 4; ++r) {
        int co = oh + qr + r;
        if (co < 18) {
          int px = ar * 32 + ni * 16 + lr;
          offL[px * 20 + co] = accA[ni][r] + ob[co];
        }
      }
    }
  }
  __syncthreads();  // offL visible; Xs/owbL dead -> Wp3/S writable

  // ======= Phase B: main conv (64o x 128px, K=576) =======
  int pixS = t >> 2, cg = t & 3;  // sampler: 128 px x 4 ch-groups of 16
  int rS = pixS >> 5;
  int wS = w0 + (pixS & 31);
  int woB = (wid >> 2) * 32, wpB = (wid & 3) * 32;

  f32x4 acc[2][2];
#pragma unroll
  for (int i = 0; i < 2; ++i)
#pragma unroll
    for (int j = 0; j < 2; ++j) acc[i][j] = f32x4{0.f, 0.f, 0.f, 0.f};

  // prologue: stage W batch0 -> Wp3 buf0 (FIX: 512 chunks/tap, 1536 total)
#pragma unroll
  for (int it = 0; it < 3; ++it) {
    int idx8 = it * 512 + t;  // 0..1535 = 3 taps x 64o x 8c8, exact
    int kb = idx8 >> 9, rem = idx8 & 511;
    int o = rem >> 3, c8 = rem & 7;
    *(f16x8*)&Wp3[swzh(kb * 4096 + o * 64 + c8 * 8)] =
        ((const f16x8*)(wb + kb * 4096))[rem];
  }

#pragma unroll
  for (int k = 0; k < 9; ++k) {
    // stage W batch (k/3)+1 one batch ahead, at k=1 and k=4 (FIX: 512 chunks/tap)
    if (k == 1 || k == 4) {
      int bt = k / 3 + 1;
#pragma unroll
      for (int it = 0; it < 3; ++it) {
        int idx8 = it * 512 + t;  // 0..1535
        int kb = idx8 >> 9, rem = idx8 & 511;
        int o = rem >> 3, c8 = rem & 7;
        *(f16x8*)&Wp3[swzh((bt & 1) * 12288 + kb * 4096 + o * 64 + c8 * 8)] =
            ((const f16x8*)(wb + (bt * 3 + kb) * 4096))[rem];
      }
    }
    // ---- sample tap k: 8 gathers + f16 interp -> S[pixS][cg*16..+16] ----
    {
      int ki = k / 3, kj = k % 3;
      float dy = offL[pixS * 20 + 2 * k];
      float dx = offL[pixS * 20 + 2 * k + 1];
      float py = dy + (float)(h0 + rS + ki - 1);
      float pxf = dx + (float)(wS + kj - 1);
      float fy = floorf(py), fx = floorf(pxf);
      float ly = py - fy, lx = pxf - fx;
      int y0 = (int)fy, x0 = (int)fx;
      int y1 = y0 + 1, x1 = x0 + 1;
      bool vy0 = (unsigned)y0 < 128u, vy1 = (unsigned)y1 < 128u;
      bool vx0 = (unsigned)x0 < 128u, vx1 = (unsigned)x1 < 128u;
      float w00 = (vy0 && vx0) ? (1.f - ly) * (1.f - lx) : 0.f;
      float w01 = (vy0 && vx1) ? (1.f - ly) * lx : 0.f;
      float w10 = (vy1 && vx0) ? ly * (1.f - lx) : 0.f;
      float w11 = (vy1 && vx1) ? ly * lx : 0.f;
      int yc0 = min(max(y0, 0), 127), yc1 = min(max(y1, 0), 127);
      int xc0 = min(max(x0, 0), 127), xc1 = min(max(x1, 0), 127);
      const _Float16* p00 = xb + (yc0 * 128 + xc0) * 64 + cg * 16;
      int dxo = (xc1 - xc0) * 64, dyo = (yc1 - yc0) * 8192;
      f16x8 ga0 = *(const f16x8*)(p00);
      f16x8 ga1 = *(const f16x8*)(p00 + 8);
      f16x8 gb0 = *(const f16x8*)(p00 + dxo);
      f16x8 gb1 = *(const f16x8*)(p00 + dxo + 8);
      f16x8 gc0 = *(const f16x8*)(p00 + dyo);
      f16x8 gc1 = *(const f16x8*)(p00 + dyo + 8);
      f16x8 gd0 = *(const f16x8*)(p00 + dyo + dxo);
      f16x8 gd1 = *(const f16x8*)(p00 + dyo + dxo + 8);
      f16x8 W00 = splat8(w00), W01 = splat8(w01);
      f16x8 W10 = splat8(w10), W11 = splat8(w11);
      f16x8 s0 = W00 * ga0 + W01 * gb0 + W10 * gc0 + W11 * gd0;
      f16x8 s1 = W00 * ga1 + W01 * gb1 + W10 * gc1 + W11 * gd1;
      int si = pixS * 64 + cg * 16;
      *(f16x8*)&S[swzh(si)] = s0;
      *(f16x8*)&S[swzh(si + 8)] = s1;
    }
    __syncthreads();  // S (and any pending W batch) ready
    // ---- MFMA tap k: A from Wp3 (resident batch), B from S ----
    {
      int wo = ((k / 3) & 1) * 12288 + (k % 3) * 4096;
#pragma unroll
      for (int ks = 0; ks < 2; ++ks) {
        int c0 = ks * 32 + quad * 8;
        f16x8 bfr[2], afr[2];
#pragma unroll
        for (int ni = 0; ni < 2; ++ni)
          bfr[ni] = *(const f16x8*)&S[swzh((wpB + ni * 16 + lr) * 64 + c0)];
#pragma unroll
        for (int mi = 0; mi < 2; ++mi)
          afr[mi] = *(const f16x8*)&Wp3[swzh(wo + (woB + mi * 16 + lr) * 64 + c0)];
#pragma unroll
        for (int mi = 0; mi < 2; ++mi)
#pragma unroll
          for (int ni = 0; ni < 2; ++ni)
            acc[mi][ni] = __builtin_amdgcn_mfma_f32_16x16x32_f16(
                afr[mi], bfr[ni], acc[mi][ni], 0, 0, 0);
      }
    }
    if (k < 8) __syncthreads();  // before next tap overwrites S
  }

  // ---- epilogue: col=lane&15 (px within 16-tile), row=quad*4+r (o) ----
  {
    int col = lane & 15;
    int qr = quad * 4;
#pragma unroll
    for (int mi = 0; mi < 2; ++mi) {
#pragma unroll
      for (int ni = 0; ni < 2; ++ni) {
#pragma unroll
        for (int r = 0; r < 4; ++r) {
          int o = woB + mi * 16 + qr + r;
          int px = wpB + ni * 16 + col;  // 0..127
          out[(((size_t)b * 64 + o) * 128 + h0 + (px >> 5)) * 128 + w0 + (px & 31)] =
              acc[mi][ni][r] + bias[o];
        }
      }
    }
  }
}

extern "C" void kernel_launch(void* const* d_in, const int* in_sizes, int n_in,
                              void* d_out, int out_size, void* d_ws,
                              size_t ws_size, hipStream_t stream) {
  const float* x = (const float*)d_in[0];       // (4,64,128,128)
  const float* ow = (const float*)d_in[1];      // (18,64,3,3)
  const float* ob = (const float*)d_in[2];      // (18,)
  const float* wt = (const float*)d_in[3];      // (64,64,3,3)
  const float* bias = (const float*)d_in[4];    // (64,)
  float* out = (float*)d_out;                   // (4,64,128,128)

  char* ws = (char*)d_ws;
  _Float16* xt = (_Float16*)ws;                      // 8,388,608 B
  _Float16* wb = (_Float16*)(ws + 8388608);          // 73,728 B
  _Float16* owb = (_Float16*)(ws + 8388608 + 73728); // 36,864 B

  k_xtprep<<<1240, 256, 0, stream>>>(x, wt, ow, xt, wb, owb);
  k_fused<<<512, 512, 0, stream>>>(xt, wb, owb, ob, bias, out);
}